// Round 6
// baseline (676.191 us; speedup 1.0000x reference)
//
#include <hip/hip_runtime.h>
#include <hip/hip_bf16.h>
#include <cstddef>
#include <cstdint>

typedef _Float16 f16;
typedef unsigned int u32;

#define Mtok  16384
#define Ncode 8192
#define Kdim  256
#define NSPLIT 8
#define NPER  (Ncode / NSPLIT)    // 1024 codes per split
#define RNCH  32                  // rescue chunks (256 codes each)
#define RT    16                  // rescue tokens per set
#define RYS   16                  // rescue grid.y

typedef f16   f16x8 __attribute__((ext_vector_type(8)));
typedef f16   f16x4 __attribute__((ext_vector_type(4)));
typedef float f32x4 __attribute__((ext_vector_type(4)));

#define LDSP(p) ((__attribute__((address_space(3))) void*)(p))
#define GPTR(p) ((const __attribute__((address_space(1))) void*)(p))

// ---------------------------------------------------------------------------
// Kernel 1: transpose z -> z_out (fp32) + sh = fp16(-2z) [Mtok][256].
// Also zeroes the rescue counter (read by later kernels; stream-ordered).
__global__ __launch_bounds__(256) void k_prep(const float* __restrict__ z,
        float* __restrict__ z_out, f16* __restrict__ sh, int* __restrict__ count) {
    __shared__ float tile[32][33];
    const int b  = blockIdx.z;
    const int c0 = blockIdx.y * 32;
    const int p0 = blockIdx.x * 32;
    const int tx = threadIdx.x;   // 0..31
    const int ty = threadIdx.y;   // 0..7
    if (b == 0 && c0 == 0 && p0 == 0 && tx == 0 && ty == 0) count[0] = 0;
    const float* src = z + ((size_t)b * Kdim + c0) * 1024 + p0;
#pragma unroll
    for (int i = 0; i < 32; i += 8)
        tile[ty + i][tx] = src[(size_t)(ty + i) * 1024 + tx];
    __syncthreads();
#pragma unroll
    for (int i = 0; i < 32; i += 8) {
        const float v = tile[tx][ty + i];
        const size_t m = (size_t)b * 1024 + p0 + ty + i;
        const int    c = c0 + tx;
        z_out[m * Kdim + c] = v;
        sh[m * Kdim + c] = (f16)(-2.0f * v);
    }
}

// ---------------------------------------------------------------------------
// Kernel 2: wnorm[n]=||w_n||^2, whc = fp16(w) in chunk-major layout
// [c=k/8][n][8] (16B pieces), and wmax = max float-bits of wnorm via signed
// atomicMax (0xAA poison is negative -> no init needed). One wave per row.
__global__ __launch_bounds__(64) void k_wsplit(const float* __restrict__ w,
        float* __restrict__ wnorm, f16* __restrict__ whc, int* __restrict__ wmax) {
    const int row  = blockIdx.x;
    const int lane = threadIdx.x;
    const float4 v = ((const float4*)(w + (size_t)row * Kdim))[lane];
    float s = v.x * v.x + v.y * v.y + v.z * v.z + v.w * v.w;
#pragma unroll
    for (int off = 32; off > 0; off >>= 1)
        s += __shfl_down(s, off, 64);
    if (lane == 0) {
        wnorm[row] = s;
        atomicMax(wmax, __float_as_int(s));   // s > 0 -> bits ordered as int
    }
    const int c   = lane >> 1;          // chunk 0..31
    const int pos = (lane & 1) * 4;
    f16x4 p;
    p[0] = (f16)v.x; p[1] = (f16)v.y; p[2] = (f16)v.z; p[3] = (f16)v.w;
    *(f16x4*)(whc + ((size_t)c * Ncode + row) * 8 + pos) = p;
}

// ---------------------------------------------------------------------------
// Kernel 3: fp16 single-pass MFMA distance GEMM + packed top-2.
// d~(m,n) = wnorm[n] + 1024 + sum sh*wh  (fp32 acc; +1024 keeps f positive
// so uint compare == float compare). key = (bits(f) & ~63) | (nt*2+j).
// TM=256 (A frags in registers), TN=32 per nt, 512 blocks (64 m x 8 splits).
__global__ __launch_bounds__(256, 2) void k_mfma(
        const f16* __restrict__ sh, const f16* __restrict__ whc,
        const float* __restrict__ wnorm,
        float* __restrict__ pv1, int* __restrict__ pi1, float* __restrict__ pv2) {
    __shared__ __align__(16) f16 Bs[32 * 256];   // [chunk][32 rows][8] = 16 KB
    const int tid  = threadIdx.x;
    const int w    = tid >> 6;          // wave 0..3
    const int lane = tid & 63;
    const int l15  = lane & 15;
    const int q    = lane >> 4;         // 0..3
    const int y    = blockIdx.x & 7;    // n-split
    const int x    = blockIdx.x >> 3;   // m-tile 0..63
    const int m0   = x * 256;
    const int n0   = y * NPER;

    // A fragments in registers: rows m0 + w*64 + i*16 + l15, k = c*32 + q*8
    f16x8 a[4][8];
#pragma unroll
    for (int i = 0; i < 4; ++i)
#pragma unroll
        for (int c = 0; c < 8; ++c)
            a[i][c] = *(const f16x8*)(sh +
                (size_t)(m0 + w * 64 + i * 16 + l15) * Kdim + c * 32 + q * 8);

    u32 u1[16], u2[16];
#pragma unroll
    for (int s = 0; s < 16; ++s) { u1[s] = 0xFFFFFFFFu; u2[s] = 0xFFFFFFFFu; }

#pragma unroll 1
    for (int nt = 0; nt < NPER / 32; ++nt) {   // 32 code-tiles of 32
        const int nb = n0 + nt * 32;
        __syncthreads();
        // stage 32 rows x 256 k (16 KB): 16 instrs, 4 per wave; each covers
        // 2 chunks (lanes 0..31 chunk c2, lanes 32..63 chunk c2+1).
#pragma unroll
        for (int ii = 0; ii < 4; ++ii) {
            const int c2 = (w * 4 + ii) * 2;
            const int ch = c2 + (lane >> 5);
            const int nr = lane & 31;
            __builtin_amdgcn_global_load_lds(
                GPTR(whc + ((size_t)ch * Ncode + nb + nr) * 8),
                LDSP(Bs + (size_t)c2 * 256), 16, 0, 0);
        }
        __syncthreads();
        f32x4 acc[4][2];
#pragma unroll
        for (int j = 0; j < 2; ++j) {
            const float wv = wnorm[nb + j * 16 + l15] + 1024.0f;
#pragma unroll
            for (int i = 0; i < 4; ++i) {
                acc[i][j][0] = wv; acc[i][j][1] = wv;
                acc[i][j][2] = wv; acc[i][j][3] = wv;
            }
        }
#pragma unroll
        for (int cc = 0; cc < 8; ++cc)
#pragma unroll
            for (int j = 0; j < 2; ++j) {
                const f16x8 b = *(const f16x8*)&Bs[(cc * 4 + q) * 256 + (j * 16 + l15) * 8];
#pragma unroll
                for (int i = 0; i < 4; ++i)
                    acc[i][j] = __builtin_amdgcn_mfma_f32_16x16x32_f16(
                        a[i][cc], b, acc[i][j], 0, 0, 0);
            }
        // packed top-2: key ascending == (trunc value, local n) lex ascending
#pragma unroll
        for (int i = 0; i < 4; ++i)
#pragma unroll
            for (int j = 0; j < 2; ++j)
#pragma unroll
                for (int r = 0; r < 4; ++r) {
                    const int s = i * 4 + r;
                    const u32 key = (__float_as_uint(acc[i][j][r]) & 0xFFFFFFC0u)
                                    | (u32)(nt * 2 + j);
                    const u32 t2 = u1[s] > key ? u1[s] : key;   // max
                    u2[s] = u2[s] < t2 ? u2[s] : t2;            // min -> 2nd
                    u1[s] = u1[s] < key ? u1[s] : key;          // min
                }
    }
    // unpack + butterfly merge across the 16 lanes sharing each row
    float v1[16], v2[16]; int i1[16];
#pragma unroll
    for (int s = 0; s < 16; ++s) {
        v1[s] = __uint_as_float(u1[s] & 0xFFFFFFC0u);
        v2[s] = __uint_as_float(u2[s] & 0xFFFFFFC0u);
        const int local = (int)(u1[s] & 63u);
        i1[s] = n0 + (local >> 1) * 32 + (local & 1) * 16 + l15;
    }
#pragma unroll
    for (int msk = 1; msk < 16; msk <<= 1) {
#pragma unroll
        for (int s = 0; s < 16; ++s) {
            const float ov1 = __shfl_xor(v1[s], msk, 64);
            const int   oi1 = __shfl_xor(i1[s], msk, 64);
            const float ov2 = __shfl_xor(v2[s], msk, 64);
            const bool  keep = (v1[s] < ov1) || (v1[s] == ov1 && i1[s] < oi1);
            const float lose = keep ? ov1 : v1[s];
            v1[s] = keep ? v1[s] : ov1;
            i1[s] = keep ? i1[s] : oi1;
            v2[s] = fminf(fminf(v2[s], ov2), lose);
        }
    }
    if (l15 == 0) {
#pragma unroll
        for (int i = 0; i < 4; ++i)
#pragma unroll
            for (int r = 0; r < 4; ++r) {
                const int s = i * 4 + r;
                const int m = m0 + w * 64 + i * 16 + q * 4 + r;
                pv1[(size_t)y * Mtok + m] = v1[s];
                pi1[(size_t)y * Mtok + m] = i1[s];
                pv2[(size_t)y * Mtok + m] = v2[s];
            }
    }
}

// ---------------------------------------------------------------------------
// Kernel 4: per-token merge of 8 split partials + rigorous flag threshold.
// One wave per token: lanes compute S2 = ||sh_t||^2, lane 0 merges + flags.
// |d~ - d| <= 2u(1+eps)*||s~||*||w~|| + (mfma-accum + key-trunc + slack)
__global__ __launch_bounds__(256) void k_merge(
        const f16* __restrict__ sh,
        const float* __restrict__ pv1, const int* __restrict__ pi1,
        const float* __restrict__ pv2, const int* __restrict__ wmax,
        int* __restrict__ fidx, int* __restrict__ flag,
        int* __restrict__ list, int* __restrict__ count) {
    const int t    = blockIdx.x * 4 + (threadIdx.x >> 6);
    const int lane = threadIdx.x & 63;
    const f16x4 p = *(const f16x4*)(sh + (size_t)t * Kdim + lane * 4);
    float s2 = 0.f;
#pragma unroll
    for (int i = 0; i < 4; ++i) { const float e = (float)p[i]; s2 = fmaf(e, e, s2); }
#pragma unroll
    for (int off = 32; off > 0; off >>= 1)
        s2 += __shfl_down(s2, off, 64);
    if (lane == 0) {
        float b1 = 3.0e38f, b2 = 3.0e38f; int bi = 0x7fffffff;
#pragma unroll
        for (int s = 0; s < NSPLIT; ++s) {
            const float v1 = pv1[(size_t)s * Mtok + t];
            const int   i1 = pi1[(size_t)s * Mtok + t];
            const float v2 = pv2[(size_t)s * Mtok + t];
            const bool  wn = (v1 < b1) || (v1 == b1 && i1 < bi);
            const float lose = wn ? b1 : v1;
            b2 = fminf(fminf(b2, v2), lose);
            b1 = wn ? v1 : b1;
            bi = wn ? i1 : bi;
        }
        fidx[t] = bi;
        const float Wm = sqrtf(__int_as_float(wmax[0]));
        const float th = 0.00205f * sqrtf(s2) * Wm + 0.12f;
        const int f = (b2 - b1 < th) ? 1 : 0;
        flag[t] = f;
        if (f) { const int pos = atomicAdd(count, 1); list[pos] = t; }
    }
}

// ---------------------------------------------------------------------------
// Kernel 5: exact fp32 rescue, code-parallel + token-batched.
// grid (32 chunks, 16): block owns 256 code rows (thread-per-row) and loops
// token sets of 16; tokens' z cached in LDS, read via same-address broadcast
// (no shuffles in the hot loop). Partial (val,idx) per (token, chunk).
__global__ __launch_bounds__(256) void k_rescue(
        const float* __restrict__ z_out, const float* __restrict__ w,
        const float* __restrict__ wnorm, const int* __restrict__ list,
        const int* __restrict__ count,
        float* __restrict__ pcv, int* __restrict__ pci) {
    __shared__ float zt[RT][Kdim];     // 16 KB
    __shared__ float dv[RT][256];      // 16 KB
    __shared__ int   ltok[RT];
    const int bx  = blockIdx.x;
    const int tid = threadIdx.x;
    const int n   = bx * 256 + tid;    // this thread's code row
    const int cnt = count[0];
    const float wn_n = wnorm[n];
    const float4* wrow = (const float4*)(w + (size_t)n * Kdim);
    for (int set = blockIdx.y; set * RT < cnt; set += RYS) {
        const int T = min(RT, cnt - set * RT);
        __syncthreads();
        if (tid < T) ltok[tid] = list[set * RT + tid];
        __syncthreads();
#pragma unroll
        for (int it = 0; it < RT; ++it) {     // stage T rows of z (coalesced)
            const int flat = it * 256 + tid;
            const int row  = flat >> 8;
            if (row < T) zt[row][flat & 255] = z_out[(size_t)ltok[row] * Kdim + (flat & 255)];
        }
        __syncthreads();
        float acc[RT];
#pragma unroll
        for (int tt = 0; tt < RT; ++tt) acc[tt] = 0.f;
#pragma unroll 2
        for (int kk = 0; kk < 64; ++kk) {
            const float4 w4 = wrow[kk];
#pragma unroll
            for (int tt = 0; tt < RT; ++tt) {
                const f32x4 z4 = *(const f32x4*)&zt[tt][kk * 4];   // broadcast
                acc[tt] = fmaf(w4.x, z4[0], fmaf(w4.y, z4[1],
                          fmaf(w4.z, z4[2], fmaf(w4.w, z4[3], acc[tt]))));
            }
        }
#pragma unroll
        for (int tt = 0; tt < RT; ++tt)
            dv[tt][tid] = wn_n - 2.0f * acc[tt];
        __syncthreads();
        if (tid < T) {        // serial argmin over 256 rows, ascending n
            float bd = 3.0e38f; int bn = 0x7fffffff;
            for (int r = 0; r < 256; ++r) {
                const float d = dv[tid][r];
                if (d < bd) { bd = d; bn = bx * 256 + r; }
            }
            pcv[(size_t)ltok[tid] * RNCH + bx] = bd;
            pci[(size_t)ltok[tid] * RNCH + bx] = bn;
        }
    }
}

// ---------------------------------------------------------------------------
// Kernel 6: gather z_q = weight[idx] + float indices; flagged tokens merge
// their 32 rescue partials in-wave first.
__global__ __launch_bounds__(256) void k_gather(
        const float* __restrict__ w, const int* __restrict__ fidx,
        const int* __restrict__ flag,
        const float* __restrict__ pcv, const int* __restrict__ pci,
        float* __restrict__ zq, float* __restrict__ idx_out) {
    const int token = blockIdx.x * 4 + (threadIdx.x >> 6);
    const int lane  = threadIdx.x & 63;
    int bi = fidx[token];
    if (flag[token]) {
        float v = 3.0e38f; int ii = 0x7fffffff;
        if (lane < RNCH) {
            v  = pcv[(size_t)token * RNCH + lane];
            ii = pci[(size_t)token * RNCH + lane];
        }
#pragma unroll
        for (int msk = 1; msk < 64; msk <<= 1) {
            const float ov = __shfl_xor(v, msk, 64);
            const int   oi = __shfl_xor(ii, msk, 64);
            if (ov < v || (ov == v && oi < ii)) { v = ov; ii = oi; }
        }
        bi = ii;
    }
    const float4 u = *(const float4*)(w + (size_t)bi * Kdim + lane * 4);
    *(float4*)(zq + (size_t)token * Kdim + lane * 4) = u;
    if (lane == 0) idx_out[token] = (float)bi;
}

// ---------------------------------------------------------------------------
extern "C" void kernel_launch(void* const* d_in, const int* in_sizes, int n_in,
                              void* d_out, int out_size, void* d_ws, size_t ws_size,
                              hipStream_t stream) {
    const float* z = (const float*)d_in[0];
    const float* w = (const float*)d_in[1];

    float* z_out  = (float*)d_out;                          // [16384, 256]
    float* zq     = z_out + (size_t)Mtok * Kdim;            // [16384, 256]
    float* idxout = zq + (size_t)Mtok * Kdim;               // [16384]

    char* ws = (char*)d_ws;
    f16*   sh    = (f16*)ws;                       ws += (size_t)Mtok * Kdim * 2;
    f16*   whc   = (f16*)ws;                       ws += (size_t)Ncode * Kdim * 2;
    float* wnorm = (float*)ws;                     ws += (size_t)Ncode * 4;
    float* pv1   = (float*)ws;                     ws += (size_t)NSPLIT * Mtok * 4;
    int*   pi1   = (int*)ws;                       ws += (size_t)NSPLIT * Mtok * 4;
    float* pv2   = (float*)ws;                     ws += (size_t)NSPLIT * Mtok * 4;
    int*   fidx  = (int*)ws;                       ws += (size_t)Mtok * 4;
    int*   flag  = (int*)ws;                       ws += (size_t)Mtok * 4;
    int*   list  = (int*)ws;                       ws += (size_t)Mtok * 4;
    int*   count = (int*)ws;                       ws += 128;
    int*   wmax  = (int*)ws;                       ws += 128;
    float* pcv   = (float*)ws;                     ws += (size_t)Mtok * RNCH * 4;
    int*   pci   = (int*)ws;                       ws += (size_t)Mtok * RNCH * 4;

    k_prep<<<dim3(1024 / 32, Kdim / 32, 16), dim3(32, 8), 0, stream>>>(z, z_out, sh, count);
    k_wsplit<<<dim3(Ncode), dim3(64), 0, stream>>>(w, wnorm, whc, wmax);
    k_mfma<<<dim3((Mtok / 256) * NSPLIT), dim3(256), 0, stream>>>(sh, whc, wnorm,
                                                                  pv1, pi1, pv2);
    k_merge<<<dim3(Mtok / 4), dim3(256), 0, stream>>>(sh, pv1, pi1, pv2, wmax,
                                                      fidx, flag, list, count);
    k_rescue<<<dim3(RNCH, RYS), dim3(256), 0, stream>>>(z_out, w, wnorm, list, count,
                                                        pcv, pci);
    k_gather<<<dim3(Mtok / 4), dim3(256), 0, stream>>>(w, fidx, flag, pcv, pci,
                                                       zq, idxout);
}